// Round 9
// baseline (207.495 us; speedup 1.0000x reference)
//
#include <hip/hip_runtime.h>
#include <stdint.h>
#include <stddef.h>

#define NB 4
#define NC 256
#define NSP 4096
#define NG 32
#define CPG 8
#define GEPS 1e-5f
#define SCALE 0.0625f  // d^-0.5, d=256
#define NROWS (NB * NSP)  // 16384 global q-rows
#define JSPLIT 4
#define ALD 264  // padded A-row stride (shorts) in proj LDS: breaks 512B-stride conflicts

typedef __attribute__((ext_vector_type(8))) short s8v;
typedef __attribute__((ext_vector_type(4))) float f4v;
typedef __attribute__((ext_vector_type(16))) float f16v;
typedef __attribute__((ext_vector_type(4))) unsigned short us4v;
typedef __attribute__((ext_vector_type(4))) unsigned int u4v;

__device__ __forceinline__ float b2f(unsigned short h) {
  union { unsigned u; float f; } x; x.u = ((unsigned)h) << 16; return x.f;
}
__device__ __forceinline__ unsigned short f2b(float f) {
  union { float f; unsigned u; } x; x.f = f;
  unsigned r = x.u + 0x7fffu + ((x.u >> 16) & 1u);
  return (unsigned short)(r >> 16);
}
// pack two f32 -> one u32 of 2 bf16 (RTZ), lo in low half
__device__ __forceinline__ unsigned packbf(float lo, float hi) {
  union { float f; unsigned u; } a, b; a.f = lo; b.f = hi;
  return (b.u & 0xffff0000u) | (a.u >> 16);
}
// pack 8 fp32 (two float4) -> s8v of bf16 (round-nearest)
__device__ __forceinline__ s8v pack8(float4 lo, float4 hi) {
  s8v r;
  ((unsigned short*)&r)[0] = f2b(lo.x);
  ((unsigned short*)&r)[1] = f2b(lo.y);
  ((unsigned short*)&r)[2] = f2b(lo.z);
  ((unsigned short*)&r)[3] = f2b(lo.w);
  ((unsigned short*)&r)[4] = f2b(hi.x);
  ((unsigned short*)&r)[5] = f2b(hi.y);
  ((unsigned short*)&r)[6] = f2b(hi.z);
  ((unsigned short*)&r)[7] = f2b(hi.w);
  return r;
}

// ---- GroupNorm one-pass: stage fp32 tile in LDS (128KB), x read ONCE ----
__global__ __launch_bounds__(512) void gn_kernel(
    const float* __restrict__ x, const float* __restrict__ w,
    const float* __restrict__ bias, unsigned short* __restrict__ xn) {
  int b = blockIdx.x >> 5;
  int g = blockIdx.x & 31;
  const float* xp = x + ((size_t)b * NC + (size_t)g * CPG) * NSP;
  int t = threadIdx.x;

  __shared__ float xs[CPG * NSP];   // 128 KB
  __shared__ float r1[512], r2[512];

  float s = 0.f, ss = 0.f;
  for (int i = 4 * t; i < CPG * NSP; i += 2048) {
    float4 v = *(const float4*)(xp + i);
    *(float4*)(xs + i) = v;
    s += v.x + v.y + v.z + v.w;
    ss += v.x * v.x + v.y * v.y + v.z * v.z + v.w * v.w;
  }
  r1[t] = s; r2[t] = ss;
  __syncthreads();
  for (int off = 256; off > 0; off >>= 1) {
    if (t < off) { r1[t] += r1[t + off]; r2[t] += r2[t + off]; }
    __syncthreads();
  }
  float mean = r1[0] * (1.f / (CPG * NSP));
  float var  = r2[0] * (1.f / (CPG * NSP)) - mean * mean;
  float rstd = rsqrtf(var + GEPS);
  float wv[CPG], bv[CPG];
  for (int c = 0; c < CPG; c++) {
    wv[c] = w[g * CPG + c] * rstd;
    bv[c] = bias[g * CPG + c] - mean * wv[c];
  }
  for (int n = t; n < NSP; n += 512) {
    s8v pk;
    for (int c = 0; c < CPG; c++) {
      float v = xs[c * NSP + n];
      ((unsigned short*)&pk)[c] = f2b(v * wv[c] + bv[c]);
    }
    *(s8v*)(xn + ((size_t)(b * NSP + n) * NC + g * CPG)) = pk;
  }
}

// ---- Fused QKV GEMM, fp32 W inline convert, vectorized epilogues ----
__global__ __launch_bounds__(256) void qkv_gemm(
    const float* __restrict__ Wf, const unsigned short* __restrict__ xnG,
    const float* __restrict__ qkvb,
    unsigned short* __restrict__ q, unsigned short* __restrict__ k,
    unsigned short* __restrict__ v) {
  const int sec = blockIdx.y >> 1;
  const int m0 = (blockIdx.y & 1) * 128;
  const int n0 = blockIdx.x * 128;
  const float* A = Wf + (size_t)sec * NC * NC;
  const unsigned short* Bt = xnG + (size_t)blockIdx.z * NSP * NC;
  unsigned short* dst = (sec == 0 ? q : (sec == 1 ? k : v)) + (size_t)blockIdx.z * NSP * NC;
  const float scl = (sec == 0) ? SCALE : 1.f;

  __shared__ unsigned short S[8192];   // As | Bs; reused as V-stage (16 KB)
  unsigned short* As = S;
  unsigned short* Bs = S + 4096;
  const int t = threadIdx.x;
  const int lane = t & 63, wave = t >> 6;
  const int wm = (wave >> 1) * 64, wn = (wave & 1) * 64;
  const int l16 = lane & 15, quad = lane >> 4;
  const int srow = t >> 2, skc = (t & 3) * 8;

  f4v acc[4][4];
  for (int mi = 0; mi < 4; mi++)
    for (int ni = 0; ni < 4; ni++)
      acc[mi][ni] = (f4v){0.f, 0.f, 0.f, 0.f};

  const float* Ag0 = A + (size_t)(m0 + srow) * NC + skc;
  const float* Ag1 = A + (size_t)(m0 + srow + 64) * NC + skc;
  const unsigned short* Bg0 = Bt + (size_t)(n0 + srow) * NC + skc;
  const unsigned short* Bg1 = Bt + (size_t)(n0 + srow + 64) * NC + skc;

  for (int k0 = 0; k0 < NC; k0 += 32) {
    s8v a0 = pack8(*(const float4*)(Ag0 + k0), *(const float4*)(Ag0 + k0 + 4));
    s8v a1 = pack8(*(const float4*)(Ag1 + k0), *(const float4*)(Ag1 + k0 + 4));
    s8v b0 = *(const s8v*)(Bg0 + k0);
    s8v b1 = *(const s8v*)(Bg1 + k0);
    __syncthreads();
    *(s8v*)(As + srow * 32 + skc) = a0;
    *(s8v*)(As + (srow + 64) * 32 + skc) = a1;
    *(s8v*)(Bs + srow * 32 + skc) = b0;
    *(s8v*)(Bs + (srow + 64) * 32 + skc) = b1;
    __syncthreads();
    s8v af[4], bfr[4];
    for (int mi = 0; mi < 4; mi++)
      af[mi] = *(const s8v*)(As + (wm + mi * 16 + l16) * 32 + quad * 8);
    for (int ni = 0; ni < 4; ni++)
      bfr[ni] = *(const s8v*)(Bs + (wn + ni * 16 + l16) * 32 + quad * 8);
    for (int mi = 0; mi < 4; mi++)
      for (int ni = 0; ni < 4; ni++)
        acc[mi][ni] = __builtin_amdgcn_mfma_f32_16x16x32_bf16(af[mi], bfr[ni], acc[mi][ni], 0, 0, 0);
  }

  if (sec < 2) {
    // Q/K: quad-pair shfl merge -> 16B stores from even quads.
    for (int mi = 0; mi < 4; mi++) {
      const int rb = m0 + wm + mi * 16 + quad * 4;
      for (int ni = 0; ni < 4; ni++) {
        const int col = n0 + wn + ni * 16 + l16;
        f4v a = acc[mi][ni];
        unsigned short pk[4];
        for (int r = 0; r < 4; r++)
          pk[r] = f2b((a[r] + qkvb[sec * NC + rb + r]) * scl);
        unsigned w0 = (unsigned)pk[0] | ((unsigned)pk[1] << 16);
        unsigned w1 = (unsigned)pk[2] | ((unsigned)pk[3] << 16);
        unsigned p0 = __shfl_xor(w0, 16, 64);
        unsigned p1 = __shfl_xor(w1, 16, 64);
        if (!(quad & 1)) {
          u4v full; full[0] = w0; full[1] = w1; full[2] = p0; full[3] = p1;
          const size_t off = (size_t)(col >> 5) * 8192 + (rb >> 4) * 512 +
                             ((rb >> 3) & 1) * 256 + (col & 31) * 8;
          *(s8v*)(dst + off) = __builtin_bit_cast(s8v, full);
        }
      }
    }
  } else {
    // V: LDS-stage in destination layout (two 16KB passes), dense 16B copy-out.
    for (int h = 0; h < 2; h++) {
      __syncthreads();
      for (int mi = 0; mi < 4; mi++) {
        const int dlb = wm + mi * 16 + quad * 4;   // local d base 0..127
        for (int nn = 0; nn < 2; nn++) {
          const int ni = 2 * h + nn;
          const int jl = wn + ni * 16 + l16;       // local token 0..127
          f4v a = acc[mi][ni];
          const int base = ((jl >> 6) & 1) * 4096 + ((jl >> 3) & 3) * 256 + (jl & 7);
          for (int r = 0; r < 4; r++) {
            const int dl = dlb + r;
            S[base + (dl >> 5) * 1024 + (dl & 31) * 8] =
                f2b(a[r] + qkvb[2 * NC + m0 + dl]);
          }
        }
      }
      __syncthreads();
      for (int i = 0; i < 4; i++) {
        const int c = i * 256 + t;
        const int jtbit = c >> 9;
        const int dgrp = (c >> 7) & 3;
        const int rest = (c & 127) * 8;
        unsigned short* gdst = dst + (size_t)(n0 / 32 + 2 * jtbit + h) * 8192 +
                               (size_t)(m0 / 32 + dgrp) * 1024 + rest;
        *(s8v*)gdst = *(const s8v*)(S + c * 8);
      }
    }
  }
}

// ---- Flash v13 == v11 exact (best: 76.3us) ----
__global__ __launch_bounds__(256, 2) void flash13_kernel(
    const unsigned short* __restrict__ q, const unsigned short* __restrict__ k,
    const unsigned short* __restrict__ v, unsigned short* __restrict__ Opart,
    float* __restrict__ Lpart) {
  const int qt = blockIdx.x, b = blockIdx.y, js = blockIdx.z;
  const size_t sNC = (size_t)NSP * NC;
  const unsigned short* qb = q + b * sNC;
  const unsigned short* kb = k + b * sNC;
  const unsigned short* vb = v + b * sNC;
  const int t = threadIdx.x, lane = t & 63, w = t >> 6;

  __shared__ unsigned short K_lds[2][16 * 512];
  __shared__ unsigned short V_lds[2][16 * 512];

  f16v zero16;
  #pragma unroll
  for (int r = 0; r < 16; r++) zero16[r] = 0.f;

  s8v qf[16];
  {
    const unsigned short* qp = qb + (size_t)(qt * 4 + w) * 8192 + lane * 8;
    #pragma unroll
    for (int kc = 0; kc < 16; kc++)
      qf[kc] = *(const s8v*)(qp + kc * 512);
  }

  f16v accO[8];
  #pragma unroll
  for (int dt = 0; dt < 8; dt++) accO[dt] = zero16;
  float l4[4] = {0.f, 0.f, 0.f, 0.f};

  const int jbeg = js * (NSP / JSPLIT);
  const int NT = (NSP / JSPLIT) / 32;

  auto stage = [&](int j0, int bufsel) {
    const size_t tb = (size_t)(j0 >> 5) * 16;
    #pragma unroll
    for (int ii = 0; ii < 8; ii++) {
      const int idx = w * 8 + ii;
      const unsigned short* gp;
      unsigned short* ld;
      if (idx < 16) {
        gp = kb + (tb + idx) * 512 + lane * 8;
        ld = &K_lds[bufsel][idx * 512];
      } else {
        const int dt = idx - 16;
        gp = vb + (tb + dt) * 512 + lane * 8;
        ld = &V_lds[bufsel][dt * 512];
      }
      __builtin_amdgcn_global_load_lds(
          (const __attribute__((address_space(1))) unsigned int*)gp,
          (__attribute__((address_space(3))) unsigned int*)ld, 16, 0, 0);
    }
  };

  stage(jbeg, 0);
  for (int jt = 0; jt < NT; jt++) {
    __syncthreads();
    if (jt + 1 < NT) stage(jbeg + (jt + 1) * 32, (jt + 1) & 1);
    const unsigned short* Kc = K_lds[jt & 1];
    const unsigned short* Vc = V_lds[jt & 1];

    f16v accS = zero16;
    #pragma unroll
    for (int kc = 0; kc < 16; kc++) {
      s8v kf = *(const s8v*)(Kc + kc * 512 + lane * 8);
      accS = __builtin_amdgcn_mfma_f32_32x32x16_bf16(kf, qf[kc], accS, 0, 0, 0);
    }

    float p[16];
    #pragma unroll
    for (int r = 0; r < 16; r++) {
      p[r] = __expf(accS[r]);
      l4[r & 3] += p[r];
    }

    u4v pw0, pw1;
    {
      unsigned a0 = packbf(p[0], p[1]),   b0 = packbf(p[4], p[5]);
      asm("v_permlane32_swap_b32 %0, %1" : "+v"(a0), "+v"(b0));
      unsigned a1 = packbf(p[2], p[3]),   b1 = packbf(p[6], p[7]);
      asm("v_permlane32_swap_b32 %0, %1" : "+v"(a1), "+v"(b1));
      unsigned a2 = packbf(p[8], p[9]),   b2 = packbf(p[12], p[13]);
      asm("v_permlane32_swap_b32 %0, %1" : "+v"(a2), "+v"(b2));
      unsigned a3 = packbf(p[10], p[11]), b3 = packbf(p[14], p[15]);
      asm("v_permlane32_swap_b32 %0, %1" : "+v"(a3), "+v"(b3));
      pw0[0] = a0; pw0[1] = a1; pw0[2] = b0; pw0[3] = b1;
      pw1[0] = a2; pw1[1] = a3; pw1[2] = b2; pw1[3] = b3;
    }
    const s8v pb0 = __builtin_bit_cast(s8v, pw0);
    const s8v pb1 = __builtin_bit_cast(s8v, pw1);

    #pragma unroll
    for (int dt = 0; dt < 8; dt++) {
      s8v vf0 = *(const s8v*)(Vc + dt * 1024 + lane * 8);
      s8v vf1 = *(const s8v*)(Vc + dt * 1024 + 512 + lane * 8);
      accO[dt] = __builtin_amdgcn_mfma_f32_32x32x16_bf16(vf0, pb0, accO[dt], 0, 0, 0);
      accO[dt] = __builtin_amdgcn_mfma_f32_32x32x16_bf16(vf1, pb1, accO[dt], 0, 0, 0);
    }
  }

  float l_acc = l4[0] + l4[1] + l4[2] + l4[3];
  const float ltot = l_acc + __shfl_xor(l_acc, 32, 64);
  const int qrow = b * NSP + qt * 128 + w * 32 + (lane & 31);
  if (lane < 32)
    Lpart[(size_t)js * NROWS + qrow] = ltot;

  unsigned short* Op = Opart + ((size_t)js * NROWS + qrow) * NC;
  const int hi = lane >> 5;
  #pragma unroll
  for (int dt = 0; dt < 8; dt++) {
    #pragma unroll
    for (int g = 0; g < 4; g++) {
      us4v pk;
      #pragma unroll
      for (int r = 0; r < 4; r++)
        pk[r] = f2b(accO[dt][g * 4 + r]);
      *(us4v*)(Op + dt * 32 + g * 8 + hi * 4) = pk;
    }
  }
}

// ---- Proj GEMM v2: JSPLIT merge folded into MFMA K-dim (K_eff = 4*256) ----
// B-staging = raw Opart DMA (global_load_lds, dbuf); A staged once (64KB LDS,
// row stride ALD=264 to break bank conflicts); 1/l applied in epilogue.
__global__ __launch_bounds__(256) void proj_gemm(
    const float* __restrict__ Wpf, const unsigned short* __restrict__ Opart,
    const float* __restrict__ Lpart, const float* __restrict__ pb,
    const float* __restrict__ x, float* __restrict__ out) {
  const int z = blockIdx.z, m0 = blockIdx.y * 128, n0 = blockIdx.x * 128;
  __shared__ unsigned short Asf[128 * ALD];      // 66 KB, bf16 weights
  __shared__ unsigned short Bsd[2][128 * 32];    // 2 x 8 KB, raw Opart slices
  const int t = threadIdx.x;
  const int lane = t & 63, wave = t >> 6;
  const int wm = (wave >> 1) * 64, wn = (wave & 1) * 64;
  const int l16 = lane & 15, quad = lane >> 4;
  const int srow = t >> 2, skc = (t & 3) * 8;

  // A: convert fp32 -> bf16 once into padded LDS tile
  for (int i = 0; i < 16; i++) {
    const int idx = i * 256 + t;          // chunk 0..4095
    const int row = idx >> 5;             // 0..127
    const int cc = (idx & 31) * 8;        // 0..248
    const float* src = Wpf + (size_t)(m0 + row) * NC + cc;
    *(s8v*)(Asf + row * ALD + cc) = pack8(*(const float4*)src, *(const float4*)(src + 4));
  }

  // per-thread 1/l for the 4 output columns this thread owns
  float inv[4];
  for (int ni = 0; ni < 4; ni++) {
    const int col = n0 + wn + ni * 16 + l16;
    float ls = 0.f;
    for (int js = 0; js < JSPLIT; js++)
      ls += Lpart[(size_t)js * NROWS + z * NSP + col];
    inv[ni] = 1.f / ls;
  }

  f4v acc[4][4];
  for (int mi = 0; mi < 4; mi++)
    for (int ni = 0; ni < 4; ni++)
      acc[mi][ni] = (f4v){0.f, 0.f, 0.f, 0.f};

  auto stageB = [&](int kk, int bufsel) {
    const int js = kk >> 3, c0 = (kk & 7) * 32;
    const unsigned short* g0 =
        Opart + ((size_t)js * NROWS + z * NSP + n0 + srow) * NC + c0 + skc;
    __builtin_amdgcn_global_load_lds(
        (const __attribute__((address_space(1))) unsigned int*)g0,
        (__attribute__((address_space(3))) unsigned int*)(Bsd[bufsel] + srow * 32 + skc),
        16, 0, 0);
    const unsigned short* g1 = g0 + (size_t)64 * NC;
    __builtin_amdgcn_global_load_lds(
        (const __attribute__((address_space(1))) unsigned int*)g1,
        (__attribute__((address_space(3))) unsigned int*)(Bsd[bufsel] + (srow + 64) * 32 + skc),
        16, 0, 0);
  };

  stageB(0, 0);
  for (int kk = 0; kk < 32; kk++) {
    __syncthreads();                       // drains vmcnt: current buf ready
    if (kk + 1 < 32) stageB(kk + 1, (kk + 1) & 1);
    const unsigned short* Bc = Bsd[kk & 1];
    const int c0 = (kk & 7) * 32;
    s8v af[4], bfr[4];
    for (int mi = 0; mi < 4; mi++)
      af[mi] = *(const s8v*)(Asf + (wm + mi * 16 + l16) * ALD + c0 + quad * 8);
    for (int ni = 0; ni < 4; ni++)
      bfr[ni] = *(const s8v*)(Bc + (wn + ni * 16 + l16) * 32 + quad * 8);
    for (int mi = 0; mi < 4; mi++)
      for (int ni = 0; ni < 4; ni++)
        acc[mi][ni] = __builtin_amdgcn_mfma_f32_16x16x32_bf16(af[mi], bfr[ni], acc[mi][ni], 0, 0, 0);
  }

  float* C = out + (size_t)z * NC * NSP;
  const float* R = x + (size_t)z * NC * NSP;
  for (int mi = 0; mi < 4; mi++) {
    const int rb = m0 + wm + mi * 16 + quad * 4;
    for (int ni = 0; ni < 4; ni++) {
      const int col = n0 + wn + ni * 16 + l16;
      f4v a = acc[mi][ni];
      for (int r = 0; r < 4; r++)
        C[(size_t)(rb + r) * NSP + col] =
            a[r] * inv[ni] + pb[rb + r] + R[(size_t)(rb + r) * NSP + col];
    }
  }
}

extern "C" void kernel_launch(void* const* d_in, const int* in_sizes, int n_in,
                              void* d_out, int out_size, void* d_ws, size_t ws_size,
                              hipStream_t stream) {
  const float* x      = (const float*)d_in[0];
  const float* norm_w = (const float*)d_in[1];
  const float* norm_b = (const float*)d_in[2];
  const float* qkv_w  = (const float*)d_in[3];
  const float* qkv_b  = (const float*)d_in[4];
  const float* proj_w = (const float*)d_in[5];
  const float* proj_b = (const float*)d_in[6];
  float* out = (float*)d_out;  // fp32 output

  char* ws = (char*)d_ws;
  char* wst = ws + (1 << 20);
  const size_t szBNC = (size_t)NB * NSP * NC * 2;  // 8.4 MB (bf16)
  unsigned short* xn = (unsigned short*)wst;
  unsigned short* q  = (unsigned short*)(wst + szBNC);    // frag-tiled, pre-scaled
  unsigned short* k  = (unsigned short*)(wst + 2 * szBNC);// frag-tiled
  unsigned short* v  = (unsigned short*)(wst + 3 * szBNC);// V^T frag-tiled
  unsigned short* Opart = (unsigned short*)(wst + 4 * szBNC);  // 33.6 MB
  float* Lpart = (float*)(wst + 4 * szBNC + (size_t)JSPLIT * NROWS * NC * 2);  // 256 KB
  // peak ws: 68.4 MB (proven-safe <= 76.6 MB)

  gn_kernel<<<dim3(NB * NG), 512, 0, stream>>>(x, norm_w, norm_b, xn);
  qkv_gemm<<<dim3(NSP / 128, 6, NB), 256, 0, stream>>>(qkv_w, xn, qkv_b, q, k, v);
  flash13_kernel<<<dim3(NSP / 128, NB, JSPLIT), 256, 0, stream>>>(q, k, v, Opart, Lpart);
  proj_gemm<<<dim3(NSP / 128, NC / 128, NB), 256, 0, stream>>>(
      proj_w, Opart, Lpart, proj_b, x, out);
}